// Round 1
// baseline (221.059 us; speedup 1.0000x reference)
//
#include <hip/hip_runtime.h>
#include <stdint.h>

#define AS1 __attribute__((address_space(1)))
#define AS3 __attribute__((address_space(3)))

typedef short short8 __attribute__((ext_vector_type(8)));
typedef __bf16 bf16x8 __attribute__((ext_vector_type(8)));
typedef float floatx4 __attribute__((ext_vector_type(4)));

__device__ __forceinline__ floatx4 mfma16(short8 a, short8 b, floatx4 c) {
  return __builtin_amdgcn_mfma_f32_16x16x32_bf16(
      __builtin_bit_cast(bf16x8, a), __builtin_bit_cast(bf16x8, b), c, 0, 0, 0);
}

__device__ __forceinline__ unsigned short f2bf(float f) {
  uint32_t u = __builtin_bit_cast(uint32_t, f);
  u = (u + 0x7FFFu + ((u >> 16) & 1u)) >> 16;
  return (unsigned short)u;
}
__device__ __forceinline__ float bf2f(unsigned short s) {
  return __builtin_bit_cast(float, (uint32_t)s << 16);
}

// ---------------------------------------------------------------------------
// Convert/pack: x (4096x1024 f32 -> bf16), Wq|Wk|Wv -> Wqkv (3072x1024 bf16),
// Wo -> bf16. 2,097,152 float4 groups total.
// ---------------------------------------------------------------------------
__global__ __launch_bounds__(256) void convert_pack(
    const float4* __restrict__ x, const float4* __restrict__ wq,
    const float4* __restrict__ wk, const float4* __restrict__ wv,
    const float4* __restrict__ wo, ushort4* __restrict__ xb,
    ushort4* __restrict__ wqkvb, ushort4* __restrict__ wob) {
  int i = blockIdx.x * 256 + threadIdx.x;
  const float4* src;
  ushort4* dst;
  if (i < (1 << 20)) {  // x: 2^20 float4
    src = x + i;
    dst = xb + i;
  } else {
    int t = i - (1 << 20);
    int r = t >> 18;  // 0..3 -> Wq,Wk,Wv,Wo (2^18 float4 each)
    int j = t & ((1 << 18) - 1);
    src = (r == 0 ? wq : r == 1 ? wk : r == 2 ? wv : wo) + j;
    dst = (r < 3) ? (wqkvb + (r << 18) + j) : (wob + j);
  }
  float4 v = *src;
  ushort4 o;
  o.x = f2bf(v.x);
  o.y = f2bf(v.y);
  o.z = f2bf(v.z);
  o.w = f2bf(v.w);
  *dst = o;
}

// ---------------------------------------------------------------------------
// GEMM: C[M][N] = A[M][K] @ B[N][K]^T (bf16 in, fp32 acc). 128x128 tile,
// BK=64, 4 waves (2x2 of 64x64). LDS stored in MFMA-frag order (chunk = 1KB =
// 64 lanes x 16B) so global_load_lds staging and ds_read_b128 frag reads are
// both conflict-free.
// ---------------------------------------------------------------------------
template <typename OutT>
__global__ __launch_bounds__(256) void gemm_bt(const unsigned short* __restrict__ A,
                                               const unsigned short* __restrict__ Bm,
                                               OutT* __restrict__ C, int N, int K) {
  __shared__ unsigned short lds[32 * 512];  // 32 chunks x 1KB (A:0-15, B:16-31)
  const int tid = threadIdx.x;
  const int lane = tid & 63;
  const int w = tid >> 6;
  const int wr = w >> 1, wc = w & 1;
  const int tm = blockIdx.x * 128, tn = blockIdx.y * 128;
  const int lrow = lane & 15;
  const int lk = (lane >> 4) * 8;

  floatx4 acc[4][4];
#pragma unroll
  for (int i = 0; i < 4; ++i)
#pragma unroll
    for (int j = 0; j < 4; ++j) acc[i][j] = floatx4{0.f, 0.f, 0.f, 0.f};

  for (int k0 = 0; k0 < K; k0 += 64) {
#pragma unroll
    for (int c = w; c < 32; c += 4) {  // each wave stages 8 chunks
      const unsigned short* g;
      if (c < 16) {
        int mt = c >> 1, ks = c & 1;
        g = A + (size_t)(tm + mt * 16 + lrow) * K + (k0 + ks * 32 + lk);
      } else {
        int cc = c - 16;
        int nt = cc >> 1, ks = cc & 1;
        g = Bm + (size_t)(tn + nt * 16 + lrow) * K + (k0 + ks * 32 + lk);
      }
      __builtin_amdgcn_global_load_lds((const AS1 uint32_t*)g,
                                       (AS3 uint32_t*)(&lds[c * 512]), 16, 0, 0);
    }
    __syncthreads();
#pragma unroll
    for (int ks = 0; ks < 2; ++ks) {
      short8 af[4], bf[4];
#pragma unroll
      for (int i = 0; i < 4; ++i)
        af[i] = *(const short8*)&lds[((wr * 4 + i) * 2 + ks) * 512 + lane * 8];
#pragma unroll
      for (int j = 0; j < 4; ++j)
        bf[j] = *(const short8*)&lds[(16 + (wc * 4 + j) * 2 + ks) * 512 + lane * 8];
#pragma unroll
      for (int i = 0; i < 4; ++i)
#pragma unroll
        for (int j = 0; j < 4; ++j) acc[i][j] = mfma16(af[i], bf[j], acc[i][j]);
    }
    __syncthreads();
  }
  const int r0 = (lane >> 4) * 4;
#pragma unroll
  for (int i = 0; i < 4; ++i)
#pragma unroll
    for (int j = 0; j < 4; ++j)
#pragma unroll
      for (int r = 0; r < 4; ++r) {
        int row = tm + wr * 64 + i * 16 + r0 + r;
        int col = tn + wc * 64 + j * 16 + lrow;
        float v = acc[i][j][r];
        if constexpr (sizeof(OutT) == 2)
          C[(size_t)row * N + col] = f2bf(v);
        else
          C[(size_t)row * N + col] = v;
      }
}

// ---------------------------------------------------------------------------
// Flash-style sink+window attention. Grid (64 q-blocks, 16 heads), 256 thr.
// Wave w owns q rows [q0+16w, q0+16w+16). Per 32-key block: QK via 4 MFMA,
// online softmax, P->LDS (C-layout -> A-layout), PV via 4 MFMA.
// qkv: 4096x3072 bf16 (Q|K|V). aout: 4096x1024 bf16.
// ---------------------------------------------------------------------------
__global__ __launch_bounds__(256) void attn_kernel(const unsigned short* __restrict__ qkv,
                                                   unsigned short* __restrict__ aout) {
  __shared__ unsigned short Klds[4 * 512];   // 4 chunks (ct,ks) x 1KB
  __shared__ unsigned short VT[64 * 40];     // V^T [d][key], row stride 40 (pad)
  __shared__ unsigned short P[4][16 * 40];   // per wave P tile, stride 40

  const int tid = threadIdx.x;
  const int lane = tid & 63;
  const int w = tid >> 6;
  const int h = blockIdx.y;
  const int q0 = blockIdx.x * 64;
  const int qa = q0 + w * 16;
  const int lrow = lane & 15;
  const int lkg = lane >> 4;

  short8 qf[2];
#pragma unroll
  for (int ks = 0; ks < 2; ++ks)
    qf[ks] = *(const short8*)&qkv[(size_t)(qa + lrow) * 3072 + h * 64 + ks * 32 + lkg * 8];

  float m_i[4], l_i[4];
  floatx4 o[4];
#pragma unroll
  for (int r = 0; r < 4; ++r) {
    m_i[r] = -1e30f;
    l_i[r] = 0.f;
  }
#pragma unroll
  for (int nt = 0; nt < 4; ++nt) o[nt] = floatx4{0.f, 0.f, 0.f, 0.f};

  const float scale = 0.125f;
  int wlo = q0 - 511;
  int kbw = 32;
  if (wlo > 32) kbw = wlo & ~31;  // first window block (block 0 = sinks)

  for (int kb = 0; kb <= q0 + 63; kb = (kb == 0) ? kbw : kb + 32) {
    __syncthreads();  // protect LDS from previous iteration's readers
    {  // stage K chunk (wave w -> chunk w): ct = w>>1, ks = w&1
      int ct = w >> 1, ks = w & 1;
      const unsigned short* g =
          &qkv[(size_t)(kb + ct * 16 + lrow) * 3072 + 1024 + h * 64 + ks * 32 + lkg * 8];
      __builtin_amdgcn_global_load_lds((const AS1 uint32_t*)g,
                                       (AS3 uint32_t*)(&Klds[w * 512]), 16, 0, 0);
    }
    {  // stage V transposed: thread handles key pair (2kp,2kp+1), d range dg*4..+4
      int kp = tid & 15, dg = tid >> 4;
      const unsigned short* g0 = &qkv[(size_t)(kb + 2 * kp) * 3072 + 2048 + h * 64 + dg * 4];
      ushort4 a = *(const ushort4*)g0;
      ushort4 b = *(const ushort4*)(g0 + 3072);
      uint32_t* vt = (uint32_t*)VT;
      vt[(dg * 4 + 0) * 20 + kp] = (uint32_t)a.x | ((uint32_t)b.x << 16);
      vt[(dg * 4 + 1) * 20 + kp] = (uint32_t)a.y | ((uint32_t)b.y << 16);
      vt[(dg * 4 + 2) * 20 + kp] = (uint32_t)a.z | ((uint32_t)b.z << 16);
      vt[(dg * 4 + 3) * 20 + kp] = (uint32_t)a.w | ((uint32_t)b.w << 16);
    }
    __syncthreads();

    // QK^T: S[16 q][32 key] as two 16x16 C-tiles
    floatx4 s[2];
#pragma unroll
    for (int ct = 0; ct < 2; ++ct) {
      s[ct] = floatx4{0.f, 0.f, 0.f, 0.f};
#pragma unroll
      for (int ks = 0; ks < 2; ++ks) {
        short8 kf = *(const short8*)&Klds[(ct * 2 + ks) * 512 + lane * 8];
        s[ct] = mfma16(qf[ks], kf, s[ct]);
      }
    }
    // mask + scale + row max
    float mx[4] = {-1e30f, -1e30f, -1e30f, -1e30f};
    float sv[2][4];
#pragma unroll
    for (int ct = 0; ct < 2; ++ct) {
      int j = kb + ct * 16 + lrow;
#pragma unroll
      for (int r = 0; r < 4; ++r) {
        int i = qa + lkg * 4 + r;
        bool vis = (j <= i) && ((j < 4) || (j >= i - 511));
        float val = vis ? s[ct][r] * scale : -1e30f;
        sv[ct][r] = val;
        mx[r] = fmaxf(mx[r], val);
      }
    }
#pragma unroll
    for (int off = 1; off < 16; off <<= 1)
#pragma unroll
      for (int r = 0; r < 4; ++r) mx[r] = fmaxf(mx[r], __shfl_xor(mx[r], off));

    float alpha[4], ps[4];
#pragma unroll
    for (int r = 0; r < 4; ++r) {
      float nm = fmaxf(m_i[r], mx[r]);
      alpha[r] = __expf(m_i[r] - nm);
      m_i[r] = nm;
      ps[r] = 0.f;
    }
#pragma unroll
    for (int ct = 0; ct < 2; ++ct)
#pragma unroll
      for (int r = 0; r < 4; ++r) {
        float p = __expf(sv[ct][r] - m_i[r]);
        unsigned short pb = f2bf(p);
        P[w][(lkg * 4 + r) * 40 + ct * 16 + lrow] = pb;
        ps[r] += bf2f(pb);  // l from the rounded p (matches PV numerics)
      }
#pragma unroll
    for (int off = 1; off < 16; off <<= 1)
#pragma unroll
      for (int r = 0; r < 4; ++r) ps[r] += __shfl_xor(ps[r], off);
#pragma unroll
    for (int r = 0; r < 4; ++r) l_i[r] = l_i[r] * alpha[r] + ps[r];

    // rescale O, then PV (P in A-layout from LDS, V^T gives B-frag contiguity)
#pragma unroll
    for (int nt = 0; nt < 4; ++nt)
#pragma unroll
      for (int r = 0; r < 4; ++r) o[nt][r] *= alpha[r];

    short8 pf = *(const short8*)&P[w][lrow * 40 + lkg * 8];
#pragma unroll
    for (int nt = 0; nt < 4; ++nt) {
      short8 vf = *(const short8*)&VT[(nt * 16 + lrow) * 40 + lkg * 8];
      o[nt] = mfma16(pf, vf, o[nt]);
    }
  }

#pragma unroll
  for (int r = 0; r < 4; ++r) l_i[r] = 1.0f / l_i[r];
#pragma unroll
  for (int nt = 0; nt < 4; ++nt)
#pragma unroll
    for (int r = 0; r < 4; ++r) {
      int row = qa + lkg * 4 + r;
      int col = h * 64 + nt * 16 + lrow;
      aout[(size_t)row * 1024 + col] = f2bf(o[nt][r] * l_i[r]);
    }
}

// ---------------------------------------------------------------------------
extern "C" void kernel_launch(void* const* d_in, const int* in_sizes, int n_in,
                              void* d_out, int out_size, void* d_ws, size_t ws_size,
                              hipStream_t stream) {
  const float* x = (const float*)d_in[0];
  const float* wq = (const float*)d_in[1];
  const float* wk = (const float*)d_in[2];
  const float* wv = (const float*)d_in[3];
  const float* wo = (const float*)d_in[4];

  char* ws = (char*)d_ws;
  unsigned short* Xb = (unsigned short*)(ws);                   // 8 MB  (4096x1024)
  unsigned short* Wqkv = (unsigned short*)(ws + (8u << 20));    // 6 MB  (3072x1024)
  unsigned short* Wob = (unsigned short*)(ws + (14u << 20));    // 2 MB  (1024x1024)
  unsigned short* QKV = (unsigned short*)(ws + (16u << 20));    // 24 MB (4096x3072)
  unsigned short* AO = (unsigned short*)(ws + (40u << 20));     // 8 MB  (4096x1024)

  convert_pack<<<8192, 256, 0, stream>>>((const float4*)x, (const float4*)wq,
                                         (const float4*)wk, (const float4*)wv,
                                         (const float4*)wo, (ushort4*)Xb,
                                         (ushort4*)Wqkv, (ushort4*)Wob);
  gemm_bt<unsigned short><<<dim3(32, 24), 256, 0, stream>>>(Xb, Wqkv, QKV, 3072, 1024);
  attn_kernel<<<dim3(64, 16), 256, 0, stream>>>(QKV, AO);
  gemm_bt<float><<<dim3(32, 8), 256, 0, stream>>>(AO, Wob, (float*)d_out, 1024, 1024);
}

// Round 2
// 220.420 us; speedup vs baseline: 1.0029x; 1.0029x over previous
//
#include <hip/hip_runtime.h>
#include <stdint.h>

#define AS1 __attribute__((address_space(1)))
#define AS3 __attribute__((address_space(3)))

typedef short short8 __attribute__((ext_vector_type(8)));
typedef unsigned short ushort8 __attribute__((ext_vector_type(8)));
typedef __bf16 bf16x8 __attribute__((ext_vector_type(8)));
typedef float floatx4 __attribute__((ext_vector_type(4)));

__device__ __forceinline__ floatx4 mfma16(short8 a, short8 b, floatx4 c) {
  return __builtin_amdgcn_mfma_f32_16x16x32_bf16(
      __builtin_bit_cast(bf16x8, a), __builtin_bit_cast(bf16x8, b), c, 0, 0, 0);
}

__device__ __forceinline__ unsigned short f2bf(float f) {
  uint32_t u = __builtin_bit_cast(uint32_t, f);
  u = (u + 0x7FFFu + ((u >> 16) & 1u)) >> 16;
  return (unsigned short)u;
}
__device__ __forceinline__ float bf2f(unsigned short s) {
  return __builtin_bit_cast(float, (uint32_t)s << 16);
}

// ---------------------------------------------------------------------------
// Convert/pack: x (4096x1024 f32 -> bf16), Wq|Wk|Wv -> Wqkv (3072x1024 bf16),
// Wo -> bf16. 2,097,152 float4 groups total.
// ---------------------------------------------------------------------------
__global__ __launch_bounds__(256) void convert_pack(
    const float4* __restrict__ x, const float4* __restrict__ wq,
    const float4* __restrict__ wk, const float4* __restrict__ wv,
    const float4* __restrict__ wo, ushort4* __restrict__ xb,
    ushort4* __restrict__ wqkvb, ushort4* __restrict__ wob) {
  int i = blockIdx.x * 256 + threadIdx.x;
  const float4* src;
  ushort4* dst;
  if (i < (1 << 20)) {  // x: 2^20 float4
    src = x + i;
    dst = xb + i;
  } else {
    int t = i - (1 << 20);
    int r = t >> 18;  // 0..3 -> Wq,Wk,Wv,Wo (2^18 float4 each)
    int j = t & ((1 << 18) - 1);
    src = (r == 0 ? wq : r == 1 ? wk : r == 2 ? wv : wo) + j;
    dst = (r < 3) ? (wqkvb + (r << 18) + j) : (wob + j);
  }
  float4 v = *src;
  ushort4 o;
  o.x = f2bf(v.x);
  o.y = f2bf(v.y);
  o.z = f2bf(v.z);
  o.w = f2bf(v.w);
  *dst = o;
}

// ---------------------------------------------------------------------------
// GEMM: C[M][N] = A[M][K] @ B[N][K]^T (bf16 in, fp32 acc). 128x128 tile,
// BK=64, 4 waves (2x2 of 64x64). LDS in MFMA-frag chunk order.
// ---------------------------------------------------------------------------
template <typename OutT>
__global__ __launch_bounds__(256) void gemm_bt(const unsigned short* __restrict__ A,
                                               const unsigned short* __restrict__ Bm,
                                               OutT* __restrict__ C, int N, int K) {
  __shared__ unsigned short lds[32 * 512];  // 32 chunks x 1KB (A:0-15, B:16-31)
  const int tid = threadIdx.x;
  const int lane = tid & 63;
  const int w = tid >> 6;
  const int wr = w >> 1, wc = w & 1;
  const int tm = blockIdx.x * 128, tn = blockIdx.y * 128;
  const int lrow = lane & 15;
  const int lk = (lane >> 4) * 8;

  floatx4 acc[4][4];
#pragma unroll
  for (int i = 0; i < 4; ++i)
#pragma unroll
    for (int j = 0; j < 4; ++j) acc[i][j] = floatx4{0.f, 0.f, 0.f, 0.f};

  for (int k0 = 0; k0 < K; k0 += 64) {
#pragma unroll
    for (int c = w; c < 32; c += 4) {  // each wave stages 8 chunks
      const unsigned short* g;
      if (c < 16) {
        int mt = c >> 1, ks = c & 1;
        g = A + (size_t)(tm + mt * 16 + lrow) * K + (k0 + ks * 32 + lk);
      } else {
        int cc = c - 16;
        int nt = cc >> 1, ks = cc & 1;
        g = Bm + (size_t)(tn + nt * 16 + lrow) * K + (k0 + ks * 32 + lk);
      }
      __builtin_amdgcn_global_load_lds((const AS1 uint32_t*)g,
                                       (AS3 uint32_t*)(&lds[c * 512]), 16, 0, 0);
    }
    __syncthreads();
#pragma unroll
    for (int ks = 0; ks < 2; ++ks) {
      short8 af[4], bf[4];
#pragma unroll
      for (int i = 0; i < 4; ++i)
        af[i] = *(const short8*)&lds[((wr * 4 + i) * 2 + ks) * 512 + lane * 8];
#pragma unroll
      for (int j = 0; j < 4; ++j)
        bf[j] = *(const short8*)&lds[(16 + (wc * 4 + j) * 2 + ks) * 512 + lane * 8];
#pragma unroll
      for (int i = 0; i < 4; ++i)
#pragma unroll
        for (int j = 0; j < 4; ++j) acc[i][j] = mfma16(af[i], bf[j], acc[i][j]);
    }
    __syncthreads();
  }
  const int r0 = (lane >> 4) * 4;
#pragma unroll
  for (int i = 0; i < 4; ++i)
#pragma unroll
    for (int j = 0; j < 4; ++j)
#pragma unroll
      for (int r = 0; r < 4; ++r) {
        int row = tm + wr * 64 + i * 16 + r0 + r;
        int col = tn + wc * 64 + j * 16 + lrow;
        float v = acc[i][j][r];
        if constexpr (sizeof(OutT) == 2)
          C[(size_t)row * N + col] = f2bf(v);
        else
          C[(size_t)row * N + col] = v;
      }
}

// ---------------------------------------------------------------------------
// Flash attention, S^T orientation. Grid (64 q-blocks of 64, 16 heads), 4
// waves; wave w owns q rows [q0+16w, +16). Key blocks of 128.
//   S^T = K·Q^T  (C-layout col = q -> per-lane softmax, 2 shuffles total)
//   O^T = V^T·P^T (A = V^T from LDS, B = P^T via within-wave LDS round trip)
// qkv: 4096x3072 bf16 (Q|K|V). aout: 4096x1024 bf16.
// ---------------------------------------------------------------------------
__global__ __launch_bounds__(256) void attn_kernel(const unsigned short* __restrict__ qkv,
                                                   unsigned short* __restrict__ aout) {
  __shared__ unsigned short Klds[16 * 512];   // 16 KB: A-frag chunks (kt,ks)
  __shared__ unsigned short VT[64 * 136];     // V^T [d][key], stride 136 (pad 8)
  __shared__ unsigned short PT[4][16 * 136];  // per-wave P^T [q][key], stride 136

  const int tid = threadIdx.x;
  const int lane = tid & 63;
  const int w = tid >> 6;
  const int h = blockIdx.y;
  const int q0 = blockIdx.x * 64;
  const int qa = q0 + w * 16;
  const int lrow = lane & 15;
  const int lkg = lane >> 4;
  const int qq = qa + lrow;   // this lane's query row
  const int qlo = qq - 511;   // window lower bound

  short8 qf[2];
#pragma unroll
  for (int ks = 0; ks < 2; ++ks)
    qf[ks] = *(const short8*)&qkv[(size_t)qq * 3072 + h * 64 + ks * 32 + lkg * 8];

  float m_i = -1e30f, l_i = 0.f;
  floatx4 o[4];
#pragma unroll
  for (int nt = 0; nt < 4; ++nt) o[nt] = floatx4{0.f, 0.f, 0.f, 0.f};

  const float scale2 = 0.125f * 1.44269504088896f;  // 1/8 * log2(e)

  int wstart = (q0 - 511 < 128) ? 128 : ((q0 - 511) & ~127);

  for (int kb = 0; kb <= q0 + 63; kb = (kb == 0) ? wstart : kb + 128) {
    __syncthreads();  // all waves done reading previous K/VT
    // --- stage K block (128 keys x 64 d) in A-frag chunk order ---
#pragma unroll
    for (int c = 0; c < 4; ++c) {
      int ch = w * 4 + c;
      int kt = ch >> 1, ks = ch & 1;
      const unsigned short* g =
          &qkv[(size_t)(kb + kt * 16 + lrow) * 3072 + 1024 + h * 64 + ks * 32 + lkg * 8];
      __builtin_amdgcn_global_load_lds((const AS1 uint32_t*)g,
                                       (AS3 uint32_t*)(&Klds[ch * 512]), 16, 0, 0);
    }
    // --- stage V^T: thread owns key pair (2kp,2kp+1), d range dg*16..+16 ---
    {
      int kp = tid & 63, dg = tid >> 6;
      const unsigned short* g0 = &qkv[(size_t)(kb + 2 * kp) * 3072 + 2048 + h * 64 + dg * 16];
      ushort8 a0 = *(const ushort8*)g0;
      ushort8 a1 = *(const ushort8*)(g0 + 8);
      ushort8 b0 = *(const ushort8*)(g0 + 3072);
      ushort8 b1 = *(const ushort8*)(g0 + 3080);
      uint32_t* vt = (uint32_t*)VT;
#pragma unroll
      for (int dd = 0; dd < 8; ++dd) {
        vt[(dg * 16 + dd) * 68 + kp] = (uint32_t)a0[dd] | ((uint32_t)b0[dd] << 16);
        vt[(dg * 16 + 8 + dd) * 68 + kp] = (uint32_t)a1[dd] | ((uint32_t)b1[dd] << 16);
      }
    }
    __syncthreads();

    // --- S^T = K·Q^T : 8 C-tiles, col = q (per-lane), row = key ---
    floatx4 s[8];
#pragma unroll
    for (int ct = 0; ct < 8; ++ct) {
      s[ct] = floatx4{0.f, 0.f, 0.f, 0.f};
#pragma unroll
      for (int ks = 0; ks < 2; ++ks) {
        short8 kf = *(const short8*)&Klds[(ct * 2 + ks) * 512 + lane * 8];
        s[ct] = mfma16(kf, qf[ks], s[ct]);
      }
    }

    // --- mask + scale (log2 domain) + per-lane max ---
    const bool full = (kb + 127 <= qa) && (kb >= qa + 15 - 511);
    float mx = -1e30f;
#pragma unroll
    for (int ct = 0; ct < 8; ++ct)
#pragma unroll
      for (int r = 0; r < 4; ++r) {
        float val = s[ct][r] * scale2;
        if (!full) {
          int key = kb + ct * 16 + lkg * 4 + r;
          bool vis = (key <= qq) && ((key < 4) || (key >= qlo));
          val = vis ? val : -1e30f;
        }
        s[ct][r] = val;
        mx = fmaxf(mx, val);
      }
    mx = fmaxf(mx, __shfl_xor(mx, 16));
    mx = fmaxf(mx, __shfl_xor(mx, 32));

    float nm = fmaxf(m_i, mx);
    float alpha = exp2f(m_i - nm);
    m_i = nm;

    // --- exp, write P^T (no barrier needed: within-wave LDS round trip) ---
    float ps = 0.f;
#pragma unroll
    for (int ct = 0; ct < 8; ++ct) {
      ushort4 pk;
      unsigned short pb;
      pb = f2bf(exp2f(s[ct][0] - m_i)); ps += bf2f(pb); pk.x = pb;
      pb = f2bf(exp2f(s[ct][1] - m_i)); ps += bf2f(pb); pk.y = pb;
      pb = f2bf(exp2f(s[ct][2] - m_i)); ps += bf2f(pb); pk.z = pb;
      pb = f2bf(exp2f(s[ct][3] - m_i)); ps += bf2f(pb); pk.w = pb;
      *(ushort4*)&PT[w][lrow * 136 + ct * 16 + lkg * 4] = pk;
    }
    ps += __shfl_xor(ps, 16);
    ps += __shfl_xor(ps, 32);
    l_i = l_i * alpha + ps;

    // --- rescale O, then O^T += V^T · P^T ---
#pragma unroll
    for (int nt = 0; nt < 4; ++nt)
#pragma unroll
      for (int r = 0; r < 4; ++r) o[nt][r] *= alpha;

#pragma unroll
    for (int kk = 0; kk < 4; ++kk) {
      short8 pf = *(const short8*)&PT[w][lrow * 136 + kk * 32 + lkg * 8];
#pragma unroll
      for (int nt = 0; nt < 4; ++nt) {
        short8 vf = *(const short8*)&VT[(nt * 16 + lrow) * 136 + kk * 32 + lkg * 8];
        o[nt] = mfma16(vf, pf, o[nt]);
      }
    }
  }

  const float inv = 1.0f / l_i;
#pragma unroll
  for (int nt = 0; nt < 4; ++nt) {
    ushort4 ok;
    ok.x = f2bf(o[nt][0] * inv);
    ok.y = f2bf(o[nt][1] * inv);
    ok.z = f2bf(o[nt][2] * inv);
    ok.w = f2bf(o[nt][3] * inv);
    *(ushort4*)&aout[(size_t)qq * 1024 + h * 64 + nt * 16 + lkg * 4] = ok;
  }
}

// ---------------------------------------------------------------------------
extern "C" void kernel_launch(void* const* d_in, const int* in_sizes, int n_in,
                              void* d_out, int out_size, void* d_ws, size_t ws_size,
                              hipStream_t stream) {
  const float* x = (const float*)d_in[0];
  const float* wq = (const float*)d_in[1];
  const float* wk = (const float*)d_in[2];
  const float* wv = (const float*)d_in[3];
  const float* wo = (const float*)d_in[4];

  char* ws = (char*)d_ws;
  unsigned short* Xb = (unsigned short*)(ws);                   // 8 MB  (4096x1024)
  unsigned short* Wqkv = (unsigned short*)(ws + (8u << 20));    // 6 MB  (3072x1024)
  unsigned short* Wob = (unsigned short*)(ws + (14u << 20));    // 2 MB  (1024x1024)
  unsigned short* QKV = (unsigned short*)(ws + (16u << 20));    // 24 MB (4096x3072)
  unsigned short* AO = (unsigned short*)(ws + (40u << 20));     // 8 MB  (4096x1024)

  convert_pack<<<8192, 256, 0, stream>>>((const float4*)x, (const float4*)wq,
                                         (const float4*)wk, (const float4*)wv,
                                         (const float4*)wo, (ushort4*)Xb,
                                         (ushort4*)Wqkv, (ushort4*)Wob);
  gemm_bt<unsigned short><<<dim3(32, 24), 256, 0, stream>>>(Xb, Wqkv, QKV, 3072, 1024);
  attn_kernel<<<dim3(64, 16), 256, 0, stream>>>(QKV, AO);
  gemm_bt<float><<<dim3(32, 8), 256, 0, stream>>>(AO, Wob, (float*)d_out, 1024, 1024);
}

// Round 4
// 201.888 us; speedup vs baseline: 1.0950x; 1.0918x over previous
//
#include <hip/hip_runtime.h>
#include <stdint.h>

#define AS1 __attribute__((address_space(1)))
#define AS3 __attribute__((address_space(3)))

typedef short short8 __attribute__((ext_vector_type(8)));
typedef unsigned short ushort8 __attribute__((ext_vector_type(8)));
typedef __bf16 bf16x8 __attribute__((ext_vector_type(8)));
typedef float floatx4 __attribute__((ext_vector_type(4)));

__device__ __forceinline__ floatx4 mfma16(short8 a, short8 b, floatx4 c) {
  return __builtin_amdgcn_mfma_f32_16x16x32_bf16(
      __builtin_bit_cast(bf16x8, a), __builtin_bit_cast(bf16x8, b), c, 0, 0, 0);
}

__device__ __forceinline__ unsigned short f2bf(float f) {
  uint32_t u = __builtin_bit_cast(uint32_t, f);
  u = (u + 0x7FFFu + ((u >> 16) & 1u)) >> 16;
  return (unsigned short)u;
}

// packed f32x2 -> bf16x2, 1 VALU instr for 2 values
__device__ __forceinline__ uint32_t cvt_pk_bf16(float a, float b) {
  uint32_t d;
  asm("v_cvt_pk_bf16_f32 %0, %1, %2" : "=v"(d) : "v"(a), "v"(b));
  return d;
}

// ---------------------------------------------------------------------------
// Convert/pack: x -> bf16, Wq|Wk|Wv -> Wqkv (3072x1024 bf16), Wo -> bf16.
// ---------------------------------------------------------------------------
__global__ __launch_bounds__(256) void convert_pack(
    const float4* __restrict__ x, const float4* __restrict__ wq,
    const float4* __restrict__ wk, const float4* __restrict__ wv,
    const float4* __restrict__ wo, ushort4* __restrict__ xb,
    ushort4* __restrict__ wqkvb, ushort4* __restrict__ wob) {
  int i = blockIdx.x * 256 + threadIdx.x;
  const float4* src;
  ushort4* dst;
  if (i < (1 << 20)) {
    src = x + i;
    dst = xb + i;
  } else {
    int t = i - (1 << 20);
    int r = t >> 18;
    int j = t & ((1 << 18) - 1);
    src = (r == 0 ? wq : r == 1 ? wk : r == 2 ? wv : wo) + j;
    dst = (r < 3) ? (wqkvb + (r << 18) + j) : (wob + j);
  }
  float4 v = *src;
  ushort4 o;
  o.x = f2bf(v.x);
  o.y = f2bf(v.y);
  o.z = f2bf(v.z);
  o.w = f2bf(v.w);
  *dst = o;
}

// ---------------------------------------------------------------------------
// GEMM 128x128 tile (QKV projection): C[M][N] = A[M][K] @ B[N][K]^T.
// ---------------------------------------------------------------------------
template <typename OutT>
__global__ __launch_bounds__(256) void gemm_bt(const unsigned short* __restrict__ A,
                                               const unsigned short* __restrict__ Bm,
                                               OutT* __restrict__ C, int N, int K) {
  __shared__ unsigned short lds[32 * 512];
  const int tid = threadIdx.x;
  const int lane = tid & 63;
  const int w = tid >> 6;
  const int wr = w >> 1, wc = w & 1;
  const int tm = blockIdx.x * 128, tn = blockIdx.y * 128;
  const int lrow = lane & 15;
  const int lk = (lane >> 4) * 8;

  floatx4 acc[4][4];
#pragma unroll
  for (int i = 0; i < 4; ++i)
#pragma unroll
    for (int j = 0; j < 4; ++j) acc[i][j] = floatx4{0.f, 0.f, 0.f, 0.f};

  for (int k0 = 0; k0 < K; k0 += 64) {
#pragma unroll
    for (int c = w; c < 32; c += 4) {
      const unsigned short* g;
      if (c < 16) {
        int mt = c >> 1, ks = c & 1;
        g = A + (size_t)(tm + mt * 16 + lrow) * K + (k0 + ks * 32 + lk);
      } else {
        int cc = c - 16;
        int nt = cc >> 1, ks = cc & 1;
        g = Bm + (size_t)(tn + nt * 16 + lrow) * K + (k0 + ks * 32 + lk);
      }
      __builtin_amdgcn_global_load_lds((const AS1 uint32_t*)g,
                                       (AS3 uint32_t*)(&lds[c * 512]), 16, 0, 0);
    }
    __syncthreads();
#pragma unroll
    for (int ks = 0; ks < 2; ++ks) {
      short8 af[4], bf[4];
#pragma unroll
      for (int i = 0; i < 4; ++i)
        af[i] = *(const short8*)&lds[((wr * 4 + i) * 2 + ks) * 512 + lane * 8];
#pragma unroll
      for (int j = 0; j < 4; ++j)
        bf[j] = *(const short8*)&lds[(16 + (wc * 4 + j) * 2 + ks) * 512 + lane * 8];
#pragma unroll
      for (int i = 0; i < 4; ++i)
#pragma unroll
        for (int j = 0; j < 4; ++j) acc[i][j] = mfma16(af[i], bf[j], acc[i][j]);
    }
    __syncthreads();
  }
  const int r0 = (lane >> 4) * 4;
#pragma unroll
  for (int i = 0; i < 4; ++i)
#pragma unroll
    for (int j = 0; j < 4; ++j)
#pragma unroll
      for (int r = 0; r < 4; ++r) {
        int row = tm + wr * 64 + i * 16 + r0 + r;
        int col = tn + wc * 64 + j * 16 + lrow;
        float v = acc[i][j][r];
        if constexpr (sizeof(OutT) == 2)
          C[(size_t)row * N + col] = f2bf(v);
        else
          C[(size_t)row * N + col] = v;
      }
}

// ---------------------------------------------------------------------------
// GEMM 64x128 tile (output projection; 512 WGs at N=1024 -> 2/CU).
// ---------------------------------------------------------------------------
__global__ __launch_bounds__(256) void gemm64(const unsigned short* __restrict__ A,
                                              const unsigned short* __restrict__ Bm,
                                              float* __restrict__ C, int N, int K) {
  __shared__ unsigned short lds[24 * 512];  // A: 0-7, B: 8-23
  const int tid = threadIdx.x;
  const int lane = tid & 63;
  const int w = tid >> 6;
  const int wr = w >> 1, wc = w & 1;
  const int tm = blockIdx.x * 64, tn = blockIdx.y * 128;
  const int lrow = lane & 15;
  const int lk = (lane >> 4) * 8;

  floatx4 acc[2][4];
#pragma unroll
  for (int i = 0; i < 2; ++i)
#pragma unroll
    for (int j = 0; j < 4; ++j) acc[i][j] = floatx4{0.f, 0.f, 0.f, 0.f};

  for (int k0 = 0; k0 < K; k0 += 64) {
#pragma unroll
    for (int c = w * 6; c < w * 6 + 6; ++c) {
      const unsigned short* g;
      if (c < 8) {
        int mt = c >> 1, ks = c & 1;
        g = A + (size_t)(tm + mt * 16 + lrow) * K + (k0 + ks * 32 + lk);
      } else {
        int cc = c - 8;
        int nt = cc >> 1, ks = cc & 1;
        g = Bm + (size_t)(tn + nt * 16 + lrow) * K + (k0 + ks * 32 + lk);
      }
      __builtin_amdgcn_global_load_lds((const AS1 uint32_t*)g,
                                       (AS3 uint32_t*)(&lds[c * 512]), 16, 0, 0);
    }
    __syncthreads();
#pragma unroll
    for (int ks = 0; ks < 2; ++ks) {
      short8 af[2], bf[4];
#pragma unroll
      for (int i = 0; i < 2; ++i)
        af[i] = *(const short8*)&lds[((wr * 2 + i) * 2 + ks) * 512 + lane * 8];
#pragma unroll
      for (int j = 0; j < 4; ++j)
        bf[j] = *(const short8*)&lds[(8 + (wc * 4 + j) * 2 + ks) * 512 + lane * 8];
#pragma unroll
      for (int i = 0; i < 2; ++i)
#pragma unroll
        for (int j = 0; j < 4; ++j) acc[i][j] = mfma16(af[i], bf[j], acc[i][j]);
    }
    __syncthreads();
  }
  const int r0 = (lane >> 4) * 4;
#pragma unroll
  for (int i = 0; i < 2; ++i)
#pragma unroll
    for (int j = 0; j < 4; ++j)
#pragma unroll
      for (int r = 0; r < 4; ++r) {
        int row = tm + (wr * 2 + i) * 16 + r0 + r;
        int col = tn + (wc * 4 + j) * 16 + lrow;
        C[(size_t)row * N + col] = acc[i][j][r];
      }
}

// ---------------------------------------------------------------------------
// Flash attention, S^T orientation, 128 queries/WG (wave: 2 sequential 16-q
// passes), 128-key blocks + 16-key sink tile. Grid (32 q-blocks, 16 heads).
// ---------------------------------------------------------------------------
__global__ __launch_bounds__(256) void attn_kernel(const unsigned short* __restrict__ qkv,
                                                   unsigned short* __restrict__ aout) {
  __shared__ unsigned short Klds[16 * 512];   // 16 KB A-frag chunks (kt,ks)
  __shared__ unsigned short VT[64 * 136];     // V^T [d][key], stride 136
  __shared__ unsigned short PT[4][16 * 136];  // per-wave P^T [q][key]

  const int tid = threadIdx.x;
  const int lane = tid & 63;
  const int w = tid >> 6;
  const int lrow = lane & 15;
  const int lkg = lane >> 4;

  // work-balance remap: complementary q-blocks across the two grid halves
  int qb, h;
  if (blockIdx.y < 8) {
    qb = blockIdx.x;
    h = blockIdx.y * 2;
  } else {
    qb = 31 - blockIdx.x;
    h = (blockIdx.y - 8) * 2 + 1;
  }
  const int q0 = qb * 128;

  short8 qf[2][2];
#pragma unroll
  for (int qt = 0; qt < 2; ++qt)
#pragma unroll
    for (int ks = 0; ks < 2; ++ks)
      qf[qt][ks] = *(const short8*)&qkv[(size_t)(q0 + qt * 64 + w * 16 + lrow) * 3072 +
                                        h * 64 + ks * 32 + lkg * 8];

  float m_i[2], l_i[2];
  floatx4 o[4][2];
#pragma unroll
  for (int qt = 0; qt < 2; ++qt) {
    m_i[qt] = -1e30f;
    l_i[qt] = 0.f;
#pragma unroll
    for (int nt = 0; nt < 4; ++nt) o[nt][qt] = floatx4{0.f, 0.f, 0.f, 0.f};
  }

  const float scale2 = 0.125f * 1.44269504088896f;  // 1/sqrt(64) * log2(e)

  // ---- sink tile: keys 0..15 (PV spans keys 0..31; stage V for 0..31 so the
  // zero-P region multiplies real data, never uninitialized LDS) ----
  if (w < 2) {  // stage K chunks 0,1 (kt=0, ks=w)
    const unsigned short* g = &qkv[(size_t)lrow * 3072 + 1024 + h * 64 + w * 32 + lkg * 8];
    __builtin_amdgcn_global_load_lds((const AS1 uint32_t*)g,
                                     (AS3 uint32_t*)(&Klds[w * 512]), 16, 0, 0);
  }
  {  // stage V^T keys 0..31
    int kp = tid & 63, dg = tid >> 6;
    if (kp < 16) {
      const unsigned short* g0 = &qkv[(size_t)(2 * kp) * 3072 + 2048 + h * 64 + dg * 16];
      ushort8 a0 = *(const ushort8*)g0;
      ushort8 a1 = *(const ushort8*)(g0 + 8);
      ushort8 b0 = *(const ushort8*)(g0 + 3072);
      ushort8 b1 = *(const ushort8*)(g0 + 3080);
      uint32_t* vt = (uint32_t*)VT;
#pragma unroll
      for (int dd = 0; dd < 8; ++dd) {
        vt[(dg * 16 + dd) * 68 + kp] = (uint32_t)a0[dd] | ((uint32_t)b0[dd] << 16);
        vt[(dg * 16 + 8 + dd) * 68 + kp] = (uint32_t)a1[dd] | ((uint32_t)b1[dd] << 16);
      }
    }
  }
  __syncthreads();

#pragma unroll
  for (int qt = 0; qt < 2; ++qt) {
    const int qq = q0 + qt * 64 + w * 16 + lrow;
    floatx4 s0 = floatx4{0.f, 0.f, 0.f, 0.f};
#pragma unroll
    for (int ks = 0; ks < 2; ++ks) {
      short8 kf = *(const short8*)&Klds[ks * 512 + lane * 8];
      s0 = mfma16(kf, qf[qt][ks], s0);
    }
    float mx = -1e30f;
    float sv[4];
#pragma unroll
    for (int r = 0; r < 4; ++r) {
      int key = lkg * 4 + r;
      bool vis = (key <= qq) && ((key < 4) || (key >= qq - 511));
      sv[r] = vis ? s0[r] * scale2 : -1e30f;
      mx = fmaxf(mx, sv[r]);
    }
    mx = fmaxf(mx, __shfl_xor(mx, 16));
    mx = fmaxf(mx, __shfl_xor(mx, 32));
    m_i[qt] = mx;  // key 0 always visible -> finite
    float p0 = exp2f(sv[0] - mx), p1 = exp2f(sv[1] - mx);
    float p2 = exp2f(sv[2] - mx), p3 = exp2f(sv[3] - mx);
    float ps = (p0 + p1) + (p2 + p3);
    *(uint2*)&PT[w][lrow * 136 + lkg * 4] = uint2{cvt_pk_bf16(p0, p1), cvt_pk_bf16(p2, p3)};
    *(uint2*)&PT[w][lrow * 136 + 16 + lkg * 4] = uint2{0u, 0u};  // keys 16..31 = 0
    ps += __shfl_xor(ps, 16);
    ps += __shfl_xor(ps, 32);
    l_i[qt] = ps;
    short8 pf = *(const short8*)&PT[w][lrow * 136 + lkg * 8];
#pragma unroll
    for (int nt = 0; nt < 4; ++nt) {
      short8 vf = *(const short8*)&VT[(nt * 16 + lrow) * 136 + lkg * 8];
      o[nt][qt] = mfma16(vf, pf, o[nt][qt]);
    }
  }

  // ---- window blocks of 128 keys ----
  int kb0 = (q0 - 511 < 16) ? 16 : (q0 - 511);
  for (int kb = kb0; kb < q0 + 128; kb += 128) {
    __syncthreads();  // all waves done with previous K/VT
#pragma unroll
    for (int c = 0; c < 4; ++c) {  // stage K: wave w -> chunks 4w..4w+3
      int ch = w * 4 + c;
      int kt = ch >> 1, ks = ch & 1;
      const unsigned short* g =
          &qkv[(size_t)(kb + kt * 16 + lrow) * 3072 + 1024 + h * 64 + ks * 32 + lkg * 8];
      __builtin_amdgcn_global_load_lds((const AS1 uint32_t*)g,
                                       (AS3 uint32_t*)(&Klds[ch * 512]), 16, 0, 0);
    }
    {  // stage V^T (128 keys)
      int kp = tid & 63, dg = tid >> 6;
      const unsigned short* g0 = &qkv[(size_t)(kb + 2 * kp) * 3072 + 2048 + h * 64 + dg * 16];
      ushort8 a0 = *(const ushort8*)g0;
      ushort8 a1 = *(const ushort8*)(g0 + 8);
      ushort8 b0 = *(const ushort8*)(g0 + 3072);
      ushort8 b1 = *(const ushort8*)(g0 + 3080);
      uint32_t* vt = (uint32_t*)VT;
#pragma unroll
      for (int dd = 0; dd < 8; ++dd) {
        vt[(dg * 16 + dd) * 68 + kp] = (uint32_t)a0[dd] | ((uint32_t)b0[dd] << 16);
        vt[(dg * 16 + 8 + dd) * 68 + kp] = (uint32_t)a1[dd] | ((uint32_t)b1[dd] << 16);
      }
    }
    __syncthreads();

#pragma unroll
    for (int qt = 0; qt < 2; ++qt) {
      const int qaT = q0 + qt * 64 + w * 16;  // wave-uniform
      const int qq = qaT + lrow;
      floatx4 s[8];
#pragma unroll
      for (int ct = 0; ct < 8; ++ct) {
        s[ct] = floatx4{0.f, 0.f, 0.f, 0.f};
#pragma unroll
        for (int ks = 0; ks < 2; ++ks) {
          short8 kf = *(const short8*)&Klds[(ct * 2 + ks) * 512 + lane * 8];
          s[ct] = mfma16(kf, qf[qt][ks], s[ct]);
        }
      }
      const bool full = (kb + 127 <= qaT) && (kb >= qaT + 15 - 511);
      float mx = -1e30f;
#pragma unroll
      for (int ct = 0; ct < 8; ++ct)
#pragma unroll
        for (int r = 0; r < 4; ++r) {
          float val = s[ct][r] * scale2;
          if (!full) {
            int key = kb + ct * 16 + lkg * 4 + r;
            bool vis = (key <= qq) && (key >= qq - 511);
            val = vis ? val : -1e30f;
          }
          s[ct][r] = val;
          mx = fmaxf(mx, val);
        }
      mx = fmaxf(mx, __shfl_xor(mx, 16));
      mx = fmaxf(mx, __shfl_xor(mx, 32));
      float nm = fmaxf(m_i[qt], mx);
      float alpha = exp2f(m_i[qt] - nm);
      m_i[qt] = nm;

      float ps = 0.f;
#pragma unroll
      for (int ct = 0; ct < 8; ++ct) {
        float p0 = exp2f(s[ct][0] - nm), p1 = exp2f(s[ct][1] - nm);
        float p2 = exp2f(s[ct][2] - nm), p3 = exp2f(s[ct][3] - nm);
        ps += (p0 + p1) + (p2 + p3);
        *(uint2*)&PT[w][lrow * 136 + ct * 16 + lkg * 4] =
            uint2{cvt_pk_bf16(p0, p1), cvt_pk_bf16(p2, p3)};
      }
      ps += __shfl_xor(ps, 16);
      ps += __shfl_xor(ps, 32);
      l_i[qt] = l_i[qt] * alpha + ps;

#pragma unroll
      for (int nt = 0; nt < 4; ++nt)
#pragma unroll
        for (int r = 0; r < 4; ++r) o[nt][qt][r] *= alpha;

#pragma unroll
      for (int kk = 0; kk < 4; ++kk) {
        short8 pf = *(const short8*)&PT[w][lrow * 136 + kk * 32 + lkg * 8];
#pragma unroll
        for (int nt = 0; nt < 4; ++nt) {
          short8 vf = *(const short8*)&VT[(nt * 16 + lrow) * 136 + kk * 32 + lkg * 8];
          o[nt][qt] = mfma16(vf, pf, o[nt][qt]);
        }
      }
    }
  }

#pragma unroll
  for (int qt = 0; qt < 2; ++qt) {
    const int qq = q0 + qt * 64 + w * 16 + lrow;
    const float inv = 1.0f / l_i[qt];
#pragma unroll
    for (int nt = 0; nt < 4; ++nt) {
      floatx4 ov = o[nt][qt];
      uint32_t lo = cvt_pk_bf16(ov[0] * inv, ov[1] * inv);
      uint32_t hi = cvt_pk_bf16(ov[2] * inv, ov[3] * inv);
      *(uint2*)&aout[(size_t)qq * 1024 + h * 64 + nt * 16 + lkg * 4] = uint2{lo, hi};
    }
  }
}

// ---------------------------------------------------------------------------
extern "C" void kernel_launch(void* const* d_in, const int* in_sizes, int n_in,
                              void* d_out, int out_size, void* d_ws, size_t ws_size,
                              hipStream_t stream) {
  const float* x = (const float*)d_in[0];
  const float* wq = (const float*)d_in[1];
  const float* wk = (const float*)d_in[2];
  const float* wv = (const float*)d_in[3];
  const float* wo = (const float*)d_in[4];

  char* ws = (char*)d_ws;
  unsigned short* Xb = (unsigned short*)(ws);                 // 8 MB
  unsigned short* Wqkv = (unsigned short*)(ws + (8u << 20));  // 6 MB
  unsigned short* Wob = (unsigned short*)(ws + (14u << 20));  // 2 MB
  unsigned short* QKV = (unsigned short*)(ws + (16u << 20));  // 24 MB
  unsigned short* AO = (unsigned short*)(ws + (40u << 20));   // 8 MB

  convert_pack<<<8192, 256, 0, stream>>>((const float4*)x, (const float4*)wq,
                                         (const float4*)wk, (const float4*)wv,
                                         (const float4*)wo, (ushort4*)Xb,
                                         (ushort4*)Wqkv, (ushort4*)Wob);
  gemm_bt<unsigned short><<<dim3(32, 24), 256, 0, stream>>>(Xb, Wqkv, QKV, 3072, 1024);
  attn_kernel<<<dim3(32, 16), 256, 0, stream>>>(QKV, AO);
  gemm64<<<dim3(64, 8), 256, 0, stream>>>(AO, Wob, (float*)d_out, 1024, 1024);
}

// Round 5
// 199.386 us; speedup vs baseline: 1.1087x; 1.0125x over previous
//
#include <hip/hip_runtime.h>
#include <stdint.h>

#define AS1 __attribute__((address_space(1)))
#define AS3 __attribute__((address_space(3)))

typedef short short8 __attribute__((ext_vector_type(8)));
typedef unsigned short ushort8 __attribute__((ext_vector_type(8)));
typedef __bf16 bf16x8 __attribute__((ext_vector_type(8)));
typedef float floatx4 __attribute__((ext_vector_type(4)));

__device__ __forceinline__ floatx4 mfma16(short8 a, short8 b, floatx4 c) {
  return __builtin_amdgcn_mfma_f32_16x16x32_bf16(
      __builtin_bit_cast(bf16x8, a), __builtin_bit_cast(bf16x8, b), c, 0, 0, 0);
}

__device__ __forceinline__ unsigned short f2bf(float f) {
  uint32_t u = __builtin_bit_cast(uint32_t, f);
  u = (u + 0x7FFFu + ((u >> 16) & 1u)) >> 16;
  return (unsigned short)u;
}

// packed f32x2 -> bf16x2, 1 VALU instr for 2 values
__device__ __forceinline__ uint32_t cvt_pk_bf16(float a, float b) {
  uint32_t d;
  asm("v_cvt_pk_bf16_f32 %0, %1, %2" : "=v"(d) : "v"(a), "v"(b));
  return d;
}

// ---------------------------------------------------------------------------
// Convert/pack: x -> bf16, Wq|Wk|Wv -> Wqkv (3072x1024 bf16), Wo -> bf16.
// ---------------------------------------------------------------------------
__global__ __launch_bounds__(256) void convert_pack(
    const float4* __restrict__ x, const float4* __restrict__ wq,
    const float4* __restrict__ wk, const float4* __restrict__ wv,
    const float4* __restrict__ wo, ushort4* __restrict__ xb,
    ushort4* __restrict__ wqkvb, ushort4* __restrict__ wob) {
  int i = blockIdx.x * 256 + threadIdx.x;
  const float4* src;
  ushort4* dst;
  if (i < (1 << 20)) {
    src = x + i;
    dst = xb + i;
  } else {
    int t = i - (1 << 20);
    int r = t >> 18;
    int j = t & ((1 << 18) - 1);
    src = (r == 0 ? wq : r == 1 ? wk : r == 2 ? wv : wo) + j;
    dst = (r < 3) ? (wqkvb + (r << 18) + j) : (wob + j);
  }
  float4 v = *src;
  ushort4 o;
  o.x = f2bf(v.x);
  o.y = f2bf(v.y);
  o.z = f2bf(v.z);
  o.w = f2bf(v.w);
  *dst = o;
}

// ---------------------------------------------------------------------------
// GEMM 128x128 tile (QKV projection): C[M][N] = A[M][K] @ B[N][K]^T.
// ---------------------------------------------------------------------------
template <typename OutT>
__global__ __launch_bounds__(256) void gemm_bt(const unsigned short* __restrict__ A,
                                               const unsigned short* __restrict__ Bm,
                                               OutT* __restrict__ C, int N, int K) {
  __shared__ unsigned short lds[32 * 512];
  const int tid = threadIdx.x;
  const int lane = tid & 63;
  const int w = tid >> 6;
  const int wr = w >> 1, wc = w & 1;
  const int tm = blockIdx.x * 128, tn = blockIdx.y * 128;
  const int lrow = lane & 15;
  const int lk = (lane >> 4) * 8;

  floatx4 acc[4][4];
#pragma unroll
  for (int i = 0; i < 4; ++i)
#pragma unroll
    for (int j = 0; j < 4; ++j) acc[i][j] = floatx4{0.f, 0.f, 0.f, 0.f};

  for (int k0 = 0; k0 < K; k0 += 64) {
#pragma unroll
    for (int c = w; c < 32; c += 4) {
      const unsigned short* g;
      if (c < 16) {
        int mt = c >> 1, ks = c & 1;
        g = A + (size_t)(tm + mt * 16 + lrow) * K + (k0 + ks * 32 + lk);
      } else {
        int cc = c - 16;
        int nt = cc >> 1, ks = cc & 1;
        g = Bm + (size_t)(tn + nt * 16 + lrow) * K + (k0 + ks * 32 + lk);
      }
      __builtin_amdgcn_global_load_lds((const AS1 uint32_t*)g,
                                       (AS3 uint32_t*)(&lds[c * 512]), 16, 0, 0);
    }
    __syncthreads();
#pragma unroll
    for (int ks = 0; ks < 2; ++ks) {
      short8 af[4], bf[4];
#pragma unroll
      for (int i = 0; i < 4; ++i)
        af[i] = *(const short8*)&lds[((wr * 4 + i) * 2 + ks) * 512 + lane * 8];
#pragma unroll
      for (int j = 0; j < 4; ++j)
        bf[j] = *(const short8*)&lds[(16 + (wc * 4 + j) * 2 + ks) * 512 + lane * 8];
#pragma unroll
      for (int i = 0; i < 4; ++i)
#pragma unroll
        for (int j = 0; j < 4; ++j) acc[i][j] = mfma16(af[i], bf[j], acc[i][j]);
    }
    __syncthreads();
  }
  const int r0 = (lane >> 4) * 4;
#pragma unroll
  for (int i = 0; i < 4; ++i)
#pragma unroll
    for (int j = 0; j < 4; ++j)
#pragma unroll
      for (int r = 0; r < 4; ++r) {
        int row = tm + wr * 64 + i * 16 + r0 + r;
        int col = tn + wc * 64 + j * 16 + lrow;
        float v = acc[i][j][r];
        if constexpr (sizeof(OutT) == 2)
          C[(size_t)row * N + col] = f2bf(v);
        else
          C[(size_t)row * N + col] = v;
      }
}

// ---------------------------------------------------------------------------
// GEMM 64x128 tile (output projection; 512 WGs at N=1024 -> 2/CU).
// ---------------------------------------------------------------------------
__global__ __launch_bounds__(256) void gemm64(const unsigned short* __restrict__ A,
                                              const unsigned short* __restrict__ Bm,
                                              float* __restrict__ C, int N, int K) {
  __shared__ unsigned short lds[24 * 512];  // A: 0-7, B: 8-23
  const int tid = threadIdx.x;
  const int lane = tid & 63;
  const int w = tid >> 6;
  const int wr = w >> 1, wc = w & 1;
  const int tm = blockIdx.x * 64, tn = blockIdx.y * 128;
  const int lrow = lane & 15;
  const int lk = (lane >> 4) * 8;

  floatx4 acc[2][4];
#pragma unroll
  for (int i = 0; i < 2; ++i)
#pragma unroll
    for (int j = 0; j < 4; ++j) acc[i][j] = floatx4{0.f, 0.f, 0.f, 0.f};

  for (int k0 = 0; k0 < K; k0 += 64) {
#pragma unroll
    for (int c = w * 6; c < w * 6 + 6; ++c) {
      const unsigned short* g;
      if (c < 8) {
        int mt = c >> 1, ks = c & 1;
        g = A + (size_t)(tm + mt * 16 + lrow) * K + (k0 + ks * 32 + lk);
      } else {
        int cc = c - 8;
        int nt = cc >> 1, ks = cc & 1;
        g = Bm + (size_t)(tn + nt * 16 + lrow) * K + (k0 + ks * 32 + lk);
      }
      __builtin_amdgcn_global_load_lds((const AS1 uint32_t*)g,
                                       (AS3 uint32_t*)(&lds[c * 512]), 16, 0, 0);
    }
    __syncthreads();
#pragma unroll
    for (int ks = 0; ks < 2; ++ks) {
      short8 af[2], bf[4];
#pragma unroll
      for (int i = 0; i < 2; ++i)
        af[i] = *(const short8*)&lds[((wr * 2 + i) * 2 + ks) * 512 + lane * 8];
#pragma unroll
      for (int j = 0; j < 4; ++j)
        bf[j] = *(const short8*)&lds[(8 + (wc * 4 + j) * 2 + ks) * 512 + lane * 8];
#pragma unroll
      for (int i = 0; i < 2; ++i)
#pragma unroll
        for (int j = 0; j < 4; ++j) acc[i][j] = mfma16(af[i], bf[j], acc[i][j]);
    }
    __syncthreads();
  }
  const int r0 = (lane >> 4) * 4;
#pragma unroll
  for (int i = 0; i < 2; ++i)
#pragma unroll
    for (int j = 0; j < 4; ++j)
#pragma unroll
      for (int r = 0; r < 4; ++r) {
        int row = tm + (wr * 2 + i) * 16 + r0 + r;
        int col = tn + (wc * 4 + j) * 16 + lrow;
        C[(size_t)row * N + col] = acc[i][j][r];
      }
}

// ---------------------------------------------------------------------------
// Flash attention, S^T orientation, 128 q/WG, 128-key blocks + 16-key sink.
// XCD-aware mapping: h = 2*(i&7) + (i>>8) -> 2 heads per XCD (K+V ~2MB fits
// 4MB L2). Complementary qb pairing balances the 2 co-resident WGs per CU.
// Software pipeline: Klds double-buffered (global_load_lds), V prefetched to
// registers; prefetches for block n+1 issue during compute of block n so the
// barrier vmcnt drain finds them landed.
// ---------------------------------------------------------------------------
__global__ __launch_bounds__(256) void attn_kernel(const unsigned short* __restrict__ qkv,
                                                   unsigned short* __restrict__ aout) {
  __shared__ unsigned short Klds[2][16 * 512];  // 2 x 16KB A-frag chunks
  __shared__ unsigned short VT[64 * 136];       // V^T [d][key], stride 136
  __shared__ unsigned short PT[4][16 * 136];    // per-wave P^T [q][key]

  const int tid = threadIdx.x;
  const int lane = tid & 63;
  const int w = tid >> 6;
  const int lrow = lane & 15;
  const int lkg = lane >> 4;

  const int i = blockIdx.x;
  const int half = i >> 8;
  const int j = (i >> 3) & 31;
  const int h = 2 * (i & 7) + half;
  const int qb = half ? (31 - j) : j;
  const int q0 = qb * 128;

  short8 qf[2][2];
#pragma unroll
  for (int qt = 0; qt < 2; ++qt)
#pragma unroll
    for (int ks = 0; ks < 2; ++ks)
      qf[qt][ks] = *(const short8*)&qkv[(size_t)(q0 + qt * 64 + w * 16 + lrow) * 3072 +
                                        h * 64 + ks * 32 + lkg * 8];

  float m_i[2], l_i[2];
  floatx4 o[4][2];
#pragma unroll
  for (int qt = 0; qt < 2; ++qt) {
    m_i[qt] = -1e30f;
    l_i[qt] = 0.f;
#pragma unroll
    for (int nt = 0; nt < 4; ++nt) o[nt][qt] = floatx4{0.f, 0.f, 0.f, 0.f};
  }

  const float scale2 = 0.125f * 1.44269504088896f;  // 1/sqrt(64) * log2(e)

  // ---- prologue: stage sink K/V; prefetch window block 0 ----
  if (w < 2) {  // sink K chunks 0,1 into Klds[0]
    const unsigned short* g = &qkv[(size_t)lrow * 3072 + 1024 + h * 64 + w * 32 + lkg * 8];
    __builtin_amdgcn_global_load_lds((const AS1 uint32_t*)g,
                                     (AS3 uint32_t*)(&Klds[0][w * 512]), 16, 0, 0);
  }
  {  // sink V^T keys 0..31 (PV spans 0..31; P=0 for 16..31)
    if (lane < 16) {
      const unsigned short* g0 = &qkv[(size_t)(2 * lane) * 3072 + 2048 + h * 64 + w * 16];
      ushort8 a0 = *(const ushort8*)g0;
      ushort8 a1 = *(const ushort8*)(g0 + 8);
      ushort8 b0 = *(const ushort8*)(g0 + 3072);
      ushort8 b1 = *(const ushort8*)(g0 + 3080);
      uint32_t* vt = (uint32_t*)VT;
#pragma unroll
      for (int dd = 0; dd < 8; ++dd) {
        vt[(w * 16 + dd) * 68 + lane] = (uint32_t)a0[dd] | ((uint32_t)b0[dd] << 16);
        vt[(w * 16 + 8 + dd) * 68 + lane] = (uint32_t)a1[dd] | ((uint32_t)b1[dd] << 16);
      }
    }
  }
  const int kb0 = (q0 - 511 < 16) ? 16 : (q0 - 511);
  // prefetch window block 0: K -> Klds[1], V -> registers
#pragma unroll
  for (int c = 0; c < 4; ++c) {
    int ch = w * 4 + c;
    int kt = ch >> 1, ks = ch & 1;
    const unsigned short* g =
        &qkv[(size_t)(kb0 + kt * 16 + lrow) * 3072 + 1024 + h * 64 + ks * 32 + lkg * 8];
    __builtin_amdgcn_global_load_lds((const AS1 uint32_t*)g,
                                     (AS3 uint32_t*)(&Klds[1][ch * 512]), 16, 0, 0);
  }
  ushort8 va0, va1, vb0, vb1;
  {
    const unsigned short* g0 = &qkv[(size_t)(kb0 + 2 * lane) * 3072 + 2048 + h * 64 + w * 16];
    va0 = *(const ushort8*)g0;
    va1 = *(const ushort8*)(g0 + 8);
    vb0 = *(const ushort8*)(g0 + 3072);
    vb1 = *(const ushort8*)(g0 + 3080);
  }
  __syncthreads();

  // ---- sink compute (keys 0..15; PV over 0..31 with P=0 padding) ----
#pragma unroll
  for (int qt = 0; qt < 2; ++qt) {
    const int qq = q0 + qt * 64 + w * 16 + lrow;
    floatx4 s0 = floatx4{0.f, 0.f, 0.f, 0.f};
#pragma unroll
    for (int ks = 0; ks < 2; ++ks) {
      short8 kf = *(const short8*)&Klds[0][ks * 512 + lane * 8];
      s0 = mfma16(kf, qf[qt][ks], s0);
    }
    float mx = -1e30f;
    float sv[4];
#pragma unroll
    for (int r = 0; r < 4; ++r) {
      int key = lkg * 4 + r;
      bool vis = (key <= qq) && ((key < 4) || (key >= qq - 511));
      sv[r] = vis ? s0[r] * scale2 : -1e30f;
      mx = fmaxf(mx, sv[r]);
    }
    mx = fmaxf(mx, __shfl_xor(mx, 16));
    mx = fmaxf(mx, __shfl_xor(mx, 32));
    m_i[qt] = mx;  // key 0 always visible -> finite
    float p0 = exp2f(sv[0] - mx), p1 = exp2f(sv[1] - mx);
    float p2 = exp2f(sv[2] - mx), p3 = exp2f(sv[3] - mx);
    float ps = (p0 + p1) + (p2 + p3);
    *(uint2*)&PT[w][lrow * 136 + lkg * 4] = uint2{cvt_pk_bf16(p0, p1), cvt_pk_bf16(p2, p3)};
    *(uint2*)&PT[w][lrow * 136 + 16 + lkg * 4] = uint2{0u, 0u};  // keys 16..31 = 0
    ps += __shfl_xor(ps, 16);
    ps += __shfl_xor(ps, 32);
    l_i[qt] = ps;
    short8 pf = *(const short8*)&PT[w][lrow * 136 + lkg * 8];
#pragma unroll
    for (int nt = 0; nt < 4; ++nt) {
      short8 vf = *(const short8*)&VT[(nt * 16 + lrow) * 136 + lkg * 8];
      o[nt][qt] = mfma16(vf, pf, o[nt][qt]);
    }
  }

  // ---- window blocks of 128 keys (pipelined) ----
  int nbuf = 1;
  for (int kb = kb0; kb < q0 + 128; kb += 128) {
    const bool hasnext = (kb + 128 < q0 + 128);
    __syncthreads();  // prev readers of VT done; this block's K/V prefetch drained (landed)
    {  // write V^T for this block from prefetched registers
      uint32_t* vt = (uint32_t*)VT;
#pragma unroll
      for (int dd = 0; dd < 8; ++dd) {
        vt[(w * 16 + dd) * 68 + lane] = (uint32_t)va0[dd] | ((uint32_t)vb0[dd] << 16);
        vt[(w * 16 + 8 + dd) * 68 + lane] = (uint32_t)va1[dd] | ((uint32_t)vb1[dd] << 16);
      }
    }
    __syncthreads();  // VT visible

    // issue prefetches for block n+1 (after the barrier so the drain above
    // never waits on them; they land during this block's compute)
    if (hasnext) {
      const int kn = kb + 128;
#pragma unroll
      for (int c = 0; c < 4; ++c) {
        int ch = w * 4 + c;
        int kt = ch >> 1, ks = ch & 1;
        const unsigned short* g =
            &qkv[(size_t)(kn + kt * 16 + lrow) * 3072 + 1024 + h * 64 + ks * 32 + lkg * 8];
        __builtin_amdgcn_global_load_lds((const AS1 uint32_t*)g,
                                         (AS3 uint32_t*)(&Klds[1 - nbuf][ch * 512]), 16, 0, 0);
      }
      const unsigned short* g0 = &qkv[(size_t)(kn + 2 * lane) * 3072 + 2048 + h * 64 + w * 16];
      va0 = *(const ushort8*)g0;
      va1 = *(const ushort8*)(g0 + 8);
      vb0 = *(const ushort8*)(g0 + 3072);
      vb1 = *(const ushort8*)(g0 + 3080);
    }

#pragma unroll
    for (int qt = 0; qt < 2; ++qt) {
      const int qaT = q0 + qt * 64 + w * 16;  // wave-uniform
      const int qq = qaT + lrow;
      floatx4 s[8];
#pragma unroll
      for (int ct = 0; ct < 8; ++ct) {
        s[ct] = floatx4{0.f, 0.f, 0.f, 0.f};
#pragma unroll
        for (int ks = 0; ks < 2; ++ks) {
          short8 kf = *(const short8*)&Klds[nbuf][(ct * 2 + ks) * 512 + lane * 8];
          s[ct] = mfma16(kf, qf[qt][ks], s[ct]);
        }
      }
      const bool full = (kb + 127 <= qaT) && (kb >= qaT + 15 - 511);
      float mx = -1e30f;
#pragma unroll
      for (int ct = 0; ct < 8; ++ct)
#pragma unroll
        for (int r = 0; r < 4; ++r) {
          float val = s[ct][r] * scale2;
          if (!full) {
            int key = kb + ct * 16 + lkg * 4 + r;
            bool vis = (key <= qq) && (key >= qq - 511);
            val = vis ? val : -1e30f;
          }
          s[ct][r] = val;
          mx = fmaxf(mx, val);
        }
      mx = fmaxf(mx, __shfl_xor(mx, 16));
      mx = fmaxf(mx, __shfl_xor(mx, 32));
      float nm = fmaxf(m_i[qt], mx);
      float alpha = exp2f(m_i[qt] - nm);
      m_i[qt] = nm;

      float ps = 0.f;
#pragma unroll
      for (int ct = 0; ct < 8; ++ct) {
        float p0 = exp2f(s[ct][0] - nm), p1 = exp2f(s[ct][1] - nm);
        float p2 = exp2f(s[ct][2] - nm), p3 = exp2f(s[ct][3] - nm);
        ps += (p0 + p1) + (p2 + p3);
        *(uint2*)&PT[w][lrow * 136 + ct * 16 + lkg * 4] =
            uint2{cvt_pk_bf16(p0, p1), cvt_pk_bf16(p2, p3)};
      }
      ps += __shfl_xor(ps, 16);
      ps += __shfl_xor(ps, 32);
      l_i[qt] = l_i[qt] * alpha + ps;

#pragma unroll
      for (int nt = 0; nt < 4; ++nt)
#pragma unroll
        for (int r = 0; r < 4; ++r) o[nt][qt][r] *= alpha;

#pragma unroll
      for (int kk = 0; kk < 4; ++kk) {
        short8 pf = *(const short8*)&PT[w][lrow * 136 + kk * 32 + lkg * 8];
#pragma unroll
        for (int nt = 0; nt < 4; ++nt) {
          short8 vf = *(const short8*)&VT[(nt * 16 + lrow) * 136 + kk * 32 + lkg * 8];
          o[nt][qt] = mfma16(vf, pf, o[nt][qt]);
        }
      }
    }
    nbuf ^= 1;
  }

#pragma unroll
  for (int qt = 0; qt < 2; ++qt) {
    const int qq = q0 + qt * 64 + w * 16 + lrow;
    const float inv = 1.0f / l_i[qt];
#pragma unroll
    for (int nt = 0; nt < 4; ++nt) {
      floatx4 ov = o[nt][qt];
      uint32_t lo = cvt_pk_bf16(ov[0] * inv, ov[1] * inv);
      uint32_t hi = cvt_pk_bf16(ov[2] * inv, ov[3] * inv);
      *(uint2*)&aout[(size_t)qq * 1024 + h * 64 + nt * 16 + lkg * 4] = uint2{lo, hi};
    }
  }
}

// ---------------------------------------------------------------------------
extern "C" void kernel_launch(void* const* d_in, const int* in_sizes, int n_in,
                              void* d_out, int out_size, void* d_ws, size_t ws_size,
                              hipStream_t stream) {
  const float* x = (const float*)d_in[0];
  const float* wq = (const float*)d_in[1];
  const float* wk = (const float*)d_in[2];
  const float* wv = (const float*)d_in[3];
  const float* wo = (const float*)d_in[4];

  char* ws = (char*)d_ws;
  unsigned short* Xb = (unsigned short*)(ws);                 // 8 MB
  unsigned short* Wqkv = (unsigned short*)(ws + (8u << 20));  // 6 MB
  unsigned short* Wob = (unsigned short*)(ws + (14u << 20));  // 2 MB
  unsigned short* QKV = (unsigned short*)(ws + (16u << 20));  // 24 MB
  unsigned short* AO = (unsigned short*)(ws + (40u << 20));   // 8 MB

  convert_pack<<<8192, 256, 0, stream>>>((const float4*)x, (const float4*)wq,
                                         (const float4*)wk, (const float4*)wv,
                                         (const float4*)wo, (ushort4*)Xb,
                                         (ushort4*)Wqkv, (ushort4*)Wob);
  gemm_bt<unsigned short><<<dim3(32, 24), 256, 0, stream>>>(Xb, Wqkv, QKV, 3072, 1024);
  attn_kernel<<<512, 256, 0, stream>>>(QKV, AO);
  gemm64<<<dim3(64, 8), 256, 0, stream>>>(AO, Wob, (float*)d_out, 1024, 1024);
}